// Round 3
// baseline (427.301 us; speedup 1.0000x reference)
//
#include <hip/hip_runtime.h>
#include <cstddef>
#include <cstdint>

// Problem constants
static constexpr int BB   = 2;
static constexpr int SS   = 384;
static constexpr int HH   = 768;
static constexpr int NHD  = 12;
static constexpr int ROWS = BB * SS;       // 768
#define SCALE_F 0.125f                     // 1/sqrt(64)

// ---------------------------------------------------------------------------
// 32x64-tile fp32 GEMM body, BK=32, register prefetch:
// C[i,o] = sum_k A[i,k]*W[o,k] + bias[o] (+ add[i,o])
// grid: (x = o-tile of 64, y = i-tile of 32), block 256
// ---------------------------------------------------------------------------
template<bool ADD>
__device__ __forceinline__ void gemm_body32(const float* __restrict__ A,
                                            const float* __restrict__ W,
                                            const float* __restrict__ bias,
                                            const float* __restrict__ addsrc,
                                            float* __restrict__ C) {
    __shared__ float aT[32][36];   // aT[k][i]
    __shared__ float wT[32][68];   // wT[k][o]
    const int tid = threadIdx.x;
    const int i0 = blockIdx.y * 32, o0 = blockIdx.x * 64;
    const int arow = tid >> 3, acol = (tid & 7) << 2;   // A: 32 rows x 32 k
    const int brow = tid >> 2, bcol = (tid & 3) << 2;   // W: 64 rows x 16 k (x2)
    const int tr = (tid >> 4) << 1;    // 0..30
    const int tc = (tid & 15) << 2;    // 0..60

    float4 av  = *(const float4*)&A[(size_t)(i0 + arow) * HH + acol];
    float4 wv0 = *(const float4*)&W[(size_t)(o0 + brow) * HH + bcol];
    float4 wv1 = *(const float4*)&W[(size_t)(o0 + brow) * HH + bcol + 16];
    float acc[2][4] = {};
    for (int k0 = 0; k0 < HH; k0 += 32) {
        __syncthreads();
        aT[acol + 0][arow] = av.x; aT[acol + 1][arow] = av.y;
        aT[acol + 2][arow] = av.z; aT[acol + 3][arow] = av.w;
        wT[bcol + 0][brow] = wv0.x; wT[bcol + 1][brow] = wv0.y;
        wT[bcol + 2][brow] = wv0.z; wT[bcol + 3][brow] = wv0.w;
        wT[bcol + 16][brow] = wv1.x; wT[bcol + 17][brow] = wv1.y;
        wT[bcol + 18][brow] = wv1.z; wT[bcol + 19][brow] = wv1.w;
        __syncthreads();
        if (k0 + 32 < HH) {   // prefetch next K-chunk
            av  = *(const float4*)&A[(size_t)(i0 + arow) * HH + k0 + 32 + acol];
            wv0 = *(const float4*)&W[(size_t)(o0 + brow) * HH + k0 + 32 + bcol];
            wv1 = *(const float4*)&W[(size_t)(o0 + brow) * HH + k0 + 48 + bcol];
        }
#pragma unroll
        for (int kk = 0; kk < 32; kk++) {
            const float2 a2 = *(const float2*)&aT[kk][tr];
            const float4 b4 = *(const float4*)&wT[kk][tc];
            const float ab[2] = {a2.x, a2.y};
            const float wb[4] = {b4.x, b4.y, b4.z, b4.w};
#pragma unroll
            for (int r = 0; r < 2; r++)
#pragma unroll
                for (int c = 0; c < 4; c++)
                    acc[r][c] = fmaf(ab[r], wb[c], acc[r][c]);
        }
    }
#pragma unroll
    for (int r = 0; r < 2; r++) {
        const int orow = i0 + tr + r;
        float4 o;
        o.x = acc[r][0] + bias[o0 + tc + 0];
        o.y = acc[r][1] + bias[o0 + tc + 1];
        o.z = acc[r][2] + bias[o0 + tc + 2];
        o.w = acc[r][3] + bias[o0 + tc + 3];
        if (ADD) {
            const float4 a4 = *(const float4*)&addsrc[(size_t)orow * HH + o0 + tc];
            o.x += a4.x; o.y += a4.y; o.z += a4.z; o.w += a4.w;
        }
        *(float4*)&C[(size_t)orow * HH + o0 + tc] = o;
    }
}

__global__ __launch_bounds__(256) void k_gemm_qkv(const float* __restrict__ A,
                                                  const float* __restrict__ Wq, const float* __restrict__ bq,
                                                  const float* __restrict__ Wk, const float* __restrict__ bk,
                                                  const float* __restrict__ Wv, const float* __restrict__ bv,
                                                  float* __restrict__ qo, float* __restrict__ ko,
                                                  float* __restrict__ vo) {
    const int z = blockIdx.z;
    const float* W = (z == 0) ? Wq : (z == 1) ? Wk : Wv;
    const float* bias = (z == 0) ? bq : (z == 1) ? bk : bv;
    float* C = (z == 0) ? qo : (z == 1) ? ko : vo;
    gemm_body32<false>(A, W, bias, nullptr, C);
}

__global__ __launch_bounds__(256) void k_gemm_out(const float* __restrict__ A,
                                                  const float* __restrict__ W,
                                                  const float* __restrict__ bias,
                                                  const float* __restrict__ addsrc,
                                                  float* __restrict__ C) {
    gemm_body32<true>(A, W, bias, addsrc, C);
}

// ---------------------------------------------------------------------------
// Merged middle kernel: grid (144, 1, 18), block 256.
//  z in [0,12):  uproj  -- U[row,h,e] = sum_d (q[row,hd]+v[h,d]) * Wr[hd,e]
//                h = z, e0 = (x%12)*64, r0 = (x/12)*64
//  z in [12,18): ac     -- sc[b,i,h,j] = sum_d (q+u).k + cb[i,h]
//                bh = (z-12)*4 + x/36, rem = x%36, i0 = (rem/6)*64, j0 = (rem%6)*64
//                cb[i,h] = sum_d q.br + v.br  (folded: sum_d qT.br - u.br + v.br)
// ---------------------------------------------------------------------------
__global__ __launch_bounds__(256) void k_mid(const float* __restrict__ q,
                                             const float* __restrict__ kk,
                                             const float* __restrict__ Wr,
                                             const float* __restrict__ vhead,
                                             const float* __restrict__ uvec,
                                             const float* __restrict__ br,
                                             float* __restrict__ U,
                                             float* __restrict__ sc) {
    __shared__ float bufA[64][68];
    __shared__ float bufB[64][68];
    __shared__ float cbl[64];
    const int tid = threadIdx.x;
    const int z = blockIdx.z;
    const int lr = tid >> 2;            // 0..63
    const int bc = (tid & 3) * 16;      // 0,16,32,48
    const int tr = (tid >> 4) << 2;
    const int tc = (tid & 15) << 2;

    if (z < 12) {
        // ---------------- uproj ----------------
        const int h = z;
        const int e0 = (blockIdx.x % 12) * 64, r0 = (blockIdx.x / 12) * 64;
#pragma unroll
        for (int m = 0; m < 4; m++) {
            const int col = bc + m * 4;
            const float4 qv = *(const float4*)&q[(size_t)(r0 + lr) * HH + h * 64 + col];
            const float4 vv = *(const float4*)&vhead[h * 64 + col];
            bufA[col + 0][lr] = qv.x + vv.x;
            bufA[col + 1][lr] = qv.y + vv.y;
            bufA[col + 2][lr] = qv.z + vv.z;
            bufA[col + 3][lr] = qv.w + vv.w;
            const float4 wv = *(const float4*)&Wr[(size_t)(h * 64 + lr) * HH + e0 + col];
            *(float4*)&bufB[lr][col] = wv;
        }
        __syncthreads();
        float acc[4][4] = {};
#pragma unroll 8
        for (int d = 0; d < 64; d++) {
            const float4 a4 = *(const float4*)&bufA[d][tr];
            const float4 b4 = *(const float4*)&bufB[d][tc];
            const float ab[4] = {a4.x, a4.y, a4.z, a4.w};
            const float bb[4] = {b4.x, b4.y, b4.z, b4.w};
#pragma unroll
            for (int r = 0; r < 4; r++)
#pragma unroll
                for (int c = 0; c < 4; c++)
                    acc[r][c] = fmaf(ab[r], bb[c], acc[r][c]);
        }
#pragma unroll
        for (int r = 0; r < 4; r++)
#pragma unroll
            for (int c = 0; c < 4; c++)
                U[(size_t)(r0 + tr + r) * (NHD * HH) + (size_t)h * HH + e0 + tc + c] = acc[r][c];
    } else {
        // ---------------- ac (+cb fold) ----------------
        const int q6 = z - 12;
        const int bh = q6 * 4 + blockIdx.x / 36;
        const int rem = blockIdx.x % 36;
        const int i0 = (rem / 6) * 64, j0 = (rem % 6) * 64;
        const int b = bh / NHD, h = bh - b * NHD;
#pragma unroll
        for (int m = 0; m < 4; m++) {
            const int col = bc + m * 4;
            const float4 qv = *(const float4*)&q[(size_t)(b * SS + i0 + lr) * HH + h * 64 + col];
            const float4 uv = *(const float4*)&uvec[h * 64 + col];
            bufA[col + 0][lr] = qv.x + uv.x;   // qT = q + u
            bufA[col + 1][lr] = qv.y + uv.y;
            bufA[col + 2][lr] = qv.z + uv.z;
            bufA[col + 3][lr] = qv.w + uv.w;
            const float4 kv = *(const float4*)&kk[(size_t)(b * SS + j0 + lr) * HH + h * 64 + col];
            bufB[col + 0][lr] = kv.x;
            bufB[col + 1][lr] = kv.y;
            bufB[col + 2][lr] = kv.z;
            bufB[col + 3][lr] = kv.w;
        }
        __syncthreads();
        // cb for the 64 i-rows of this tile (wave 0 only)
        if (tid < 64) {
            const int d = tid;
            const float brv = br[h * 64 + d];
            float pu = uvec[h * 64 + d] * brv;
            float pv = vhead[h * 64 + d] * brv;
#pragma unroll
            for (int off = 1; off < 64; off <<= 1) {
                pu += __shfl_xor(pu, off);
                pv += __shfl_xor(pv, off);
            }
            float s = 0.f;
            for (int d2 = 0; d2 < 64; d2++)
                s = fmaf(bufA[d2][tid], br[h * 64 + d2], s);   // sum (q+u).br
            cbl[tid] = s - pu + pv;                            // sum q.br + v.br
        }
        float acc[4][4] = {};
#pragma unroll 8
        for (int d = 0; d < 64; d++) {
            const float4 a4 = *(const float4*)&bufA[d][tr];
            const float4 b4 = *(const float4*)&bufB[d][tc];
            const float ab[4] = {a4.x, a4.y, a4.z, a4.w};
            const float bb[4] = {b4.x, b4.y, b4.z, b4.w};
#pragma unroll
            for (int r = 0; r < 4; r++)
#pragma unroll
                for (int c = 0; c < 4; c++)
                    acc[r][c] = fmaf(ab[r], bb[c], acc[r][c]);
        }
        __syncthreads();
#pragma unroll
        for (int r = 0; r < 4; r++) {
            const int i = i0 + tr + r;
            const float cbr = cbl[tr + r];
            float4 o;
            o.x = acc[r][0] + cbr; o.y = acc[r][1] + cbr;
            o.z = acc[r][2] + cbr; o.w = acc[r][3] + cbr;
            *(float4*)&sc[((size_t)(b * SS + i) * NHD + h) * SS + j0 + tc] = o;
        }
    }
}

// ---------------------------------------------------------------------------
// BD + softmax: one block per (b,i), 256 threads (4 waves), U read from L2.
// LDS = 20.3 KB -> >=3 blocks/CU -> all 768 blocks co-resident (no tail).
// ---------------------------------------------------------------------------
__global__ __launch_bounds__(256) void k_bd(const float* __restrict__ rpe,
                                            const float* __restrict__ U,
                                            const int* __restrict__ mask,
                                            float* __restrict__ scP) {
    const int i = blockIdx.x, b = blockIdx.y;
    const int row = b * SS + i;
    const int tid = threadIdx.x;

    __shared__ float sc[NHD][392];     // 18.4 KB
    __shared__ float extl[SS];         // 1.5 KB

    float* plane = scP + (size_t)row * NHD * SS;

    // stage AC scores + mask ext
    for (int t = tid; t < NHD * 96; t += 256) {
        const int h = t / 96, c4 = (t - h * 96) << 2;
        *(float4*)&sc[h][c4] = *(const float4*)&plane[h * SS + c4];
    }
    for (int t = tid; t < SS; t += 256)
        extl[t] = (1.0f - (float)mask[b * SS + t]) * (-1e18f);
    __syncthreads();

    const int wave = tid >> 6, lane = tid & 63;
    const int jsub = lane >> 3;      // 0..7
    const int elane = lane & 7;      // 0..7
    const float* rrow = rpe + (size_t)row * SS * HH;
    const float* Urow = U + (size_t)row * (NHD * HH) + (elane << 2);

    for (int g = wave; g < 12; g += 4) {
        const int jbase = g * 32 + jsub;
        const float* rp0 = rrow + (size_t)jbase * HH + (elane << 2);
        float acc[4][NHD] = {};
        float4 n0 = *(const float4*)(rp0);
        float4 n1 = *(const float4*)(rp0 + 8 * HH);
        float4 n2 = *(const float4*)(rp0 + 16 * HH);
        float4 n3 = *(const float4*)(rp0 + 24 * HH);
        for (int ec = 0; ec < 24; ec++) {
            const float4 t0 = n0, t1 = n1, t2 = n2, t3 = n3;
            if (ec < 23) {
                const float* rpn = rp0 + ((ec + 1) << 5);
                n0 = *(const float4*)(rpn);
                n1 = *(const float4*)(rpn + 8 * HH);
                n2 = *(const float4*)(rpn + 16 * HH);
                n3 = *(const float4*)(rpn + 24 * HH);
            }
            const float rb[4][4] = {{t0.x, t0.y, t0.z, t0.w},
                                    {t1.x, t1.y, t1.z, t1.w},
                                    {t2.x, t2.y, t2.z, t2.w},
                                    {t3.x, t3.y, t3.z, t3.w}};
            const float* up = Urow + (ec << 5);
#pragma unroll
            for (int h = 0; h < NHD; h++) {
                const float4 uv = *(const float4*)&up[h * HH];
                const float ub[4] = {uv.x, uv.y, uv.z, uv.w};
#pragma unroll
                for (int rr = 0; rr < 4; rr++)
#pragma unroll
                    for (int c = 0; c < 4; c++)
                        acc[rr][h] = fmaf(rb[rr][c], ub[c], acc[rr][h]);
            }
        }
#pragma unroll
        for (int rr = 0; rr < 4; rr++)
#pragma unroll
            for (int h = 0; h < NHD; h++) {
                float a = acc[rr][h];
                a += __shfl_xor(a, 1);
                a += __shfl_xor(a, 2);
                a += __shfl_xor(a, 4);
                acc[rr][h] = a;
            }
        if (elane == 0) {
#pragma unroll
            for (int rr = 0; rr < 4; rr++) {
                const int j = jbase + (rr << 3);
#pragma unroll
                for (int h = 0; h < NHD; h++)
                    sc[h][j] += acc[rr][h];
            }
        }
    }
    __syncthreads();

    // ---- fused softmax (scale + mask), write P to plane ----
    for (int h = wave; h < NHD; h += 4) {
        float vbuf[6];
        float m = -1e30f;
#pragma unroll
        for (int t2 = 0; t2 < 6; t2++) {
            vbuf[t2] = sc[h][lane + t2 * 64] * SCALE_F + extl[lane + t2 * 64];
            m = fmaxf(m, vbuf[t2]);
        }
#pragma unroll
        for (int off = 1; off < 64; off <<= 1) m = fmaxf(m, __shfl_xor(m, off));
        float ssum = 0.f;
#pragma unroll
        for (int t2 = 0; t2 < 6; t2++) {
            const float e = __expf(vbuf[t2] - m);
            vbuf[t2] = e;
            ssum += e;
        }
#pragma unroll
        for (int off = 1; off < 64; off <<= 1) ssum += __shfl_xor(ssum, off);
        const float inv = 1.0f / ssum;
#pragma unroll
        for (int t2 = 0; t2 < 6; t2++)
            plane[h * SS + lane + t2 * 64] = vbuf[t2] * inv;
    }
}

// ---------------------------------------------------------------------------
// PV GEMM: ctx[b,i,h*64+d] = sum_j P[b,i,h,j] * val[b,j,h*64+d]
// grid: (itile 6, b*NH 24), block 256
// ---------------------------------------------------------------------------
__global__ __launch_bounds__(256) void k_pv(const float* __restrict__ P,
                                            const float* __restrict__ val,
                                            float* __restrict__ ctx) {
    const int bh = blockIdx.y;
    const int b = bh / NHD, h = bh - b * NHD;
    const int i0 = blockIdx.x * 64;
    __shared__ float pT[64][68];   // pT[j][i]
    __shared__ float vB[64][68];   // vB[j][d]
    const int tid = threadIdx.x;
    const int lr = tid >> 2;
    const int bc = (tid & 3) * 16;
    const int tr = (tid >> 4) << 2;
    const int tc = (tid & 15) << 2;

    float4 pv[4], vv[4];
#pragma unroll
    for (int m = 0; m < 4; m++) {
        const int col = bc + m * 4;
        pv[m] = *(const float4*)&P[((size_t)(b * SS + i0 + lr) * NHD + h) * SS + col];
        vv[m] = *(const float4*)&val[(size_t)(b * SS + lr) * HH + h * 64 + col];
    }
    float acc[4][4] = {};
    for (int jt = 0; jt < SS; jt += 64) {
        __syncthreads();
#pragma unroll
        for (int m = 0; m < 4; m++) {
            const int col = bc + m * 4;
            pT[col + 0][lr] = pv[m].x; pT[col + 1][lr] = pv[m].y;
            pT[col + 2][lr] = pv[m].z; pT[col + 3][lr] = pv[m].w;
            *(float4*)&vB[lr][col] = vv[m];
        }
        __syncthreads();
        if (jt + 64 < SS) {
#pragma unroll
            for (int m = 0; m < 4; m++) {
                const int col = bc + m * 4;
                pv[m] = *(const float4*)&P[((size_t)(b * SS + i0 + lr) * NHD + h) * SS + jt + 64 + col];
                vv[m] = *(const float4*)&val[(size_t)(b * SS + jt + 64 + lr) * HH + h * 64 + col];
            }
        }
#pragma unroll 8
        for (int jj = 0; jj < 64; jj++) {
            const float4 a4 = *(const float4*)&pT[jj][tr];
            const float4 b4 = *(const float4*)&vB[jj][tc];
            const float ab[4] = {a4.x, a4.y, a4.z, a4.w};
            const float bb[4] = {b4.x, b4.y, b4.z, b4.w};
#pragma unroll
            for (int r = 0; r < 4; r++)
#pragma unroll
                for (int c = 0; c < 4; c++)
                    acc[r][c] = fmaf(ab[r], bb[c], acc[r][c]);
        }
    }
#pragma unroll
    for (int r = 0; r < 4; r++) {
        float4 o;
        o.x = acc[r][0]; o.y = acc[r][1]; o.z = acc[r][2]; o.w = acc[r][3];
        *(float4*)&ctx[(size_t)(b * SS + i0 + tr + r) * HH + h * 64 + tc] = o;
    }
}

// ---------------------------------------------------------------------------
// LayerNorm over last dim (768) per row
// ---------------------------------------------------------------------------
__global__ __launch_bounds__(256) void k_ln(const float* __restrict__ x,
                                            const float* __restrict__ g,
                                            const float* __restrict__ bta,
                                            float* __restrict__ o) {
    const int row = blockIdx.x;
    const int tid = threadIdx.x;
    const float* xr = x + (size_t)row * HH;
    __shared__ float red[4];
    const float v0 = xr[tid], v1 = xr[tid + 256], v2 = xr[tid + 512];
    float s = v0 + v1 + v2;
#pragma unroll
    for (int off = 1; off < 64; off <<= 1) s += __shfl_xor(s, off);
    if ((tid & 63) == 0) red[tid >> 6] = s;
    __syncthreads();
    const float mean = (red[0] + red[1] + red[2] + red[3]) * (1.0f / 768.0f);
    const float d0 = v0 - mean, d1 = v1 - mean, d2 = v2 - mean;
    float sq = d0 * d0 + d1 * d1 + d2 * d2;
#pragma unroll
    for (int off = 1; off < 64; off <<= 1) sq += __shfl_xor(sq, off);
    __syncthreads();
    if ((tid & 63) == 0) red[tid >> 6] = sq;
    __syncthreads();
    const float var = (red[0] + red[1] + red[2] + red[3]) * (1.0f / 768.0f);
    const float inv = rsqrtf(var + 1e-6f);
    o[(size_t)row * HH + tid]       = d0 * inv * g[tid]       + bta[tid];
    o[(size_t)row * HH + tid + 256] = d1 * inv * g[tid + 256] + bta[tid + 256];
    o[(size_t)row * HH + tid + 512] = d2 * inv * g[tid + 512] + bta[tid + 512];
}

// ---------------------------------------------------------------------------
extern "C" void kernel_launch(void* const* d_in, const int* in_sizes, int n_in,
                              void* d_out, int out_size, void* d_ws, size_t ws_size,
                              hipStream_t stream) {
    (void)in_sizes; (void)n_in; (void)out_size; (void)ws_size;
    const float* hs   = (const float*)d_in[0];
    const int*   mask = (const int*)d_in[1];
    const float* rpe  = (const float*)d_in[2];
    const float* Wq = (const float*)d_in[3];  const float* bq = (const float*)d_in[4];
    const float* Wk = (const float*)d_in[5];  const float* bk = (const float*)d_in[6];
    const float* Wv = (const float*)d_in[7];  const float* bv = (const float*)d_in[8];
    const float* Wr = (const float*)d_in[9];  const float* br = (const float*)d_in[10];
    const float* u  = (const float*)d_in[11]; const float* v  = (const float*)d_in[12];
    const float* Wf = (const float*)d_in[13]; const float* bf = (const float*)d_in[14];
    const float* lng = (const float*)d_in[15]; const float* lnb = (const float*)d_in[16];
    float* out = (float*)d_out;

    float* wsf     = (float*)d_ws;
    float* q_ws    = wsf;                              // 589824
    float* k_ws    = q_ws   + (size_t)ROWS * HH;
    float* v_ws    = k_ws   + (size_t)ROWS * HH;
    float* ctx_ws  = v_ws   + (size_t)ROWS * HH;
    float* lnin_ws = ctx_ws + (size_t)ROWS * HH;
    float* U_ws    = lnin_ws + (size_t)ROWS * HH;      // 7077888
    float* sc_ws   = U_ws   + (size_t)ROWS * NHD * HH; // 3538944 (scores -> P)

    k_gemm_qkv<<<dim3(12, 24, 3), 256, 0, stream>>>(hs, Wq, bq, Wk, bk, Wv, bv,
                                                    q_ws, k_ws, v_ws);
    k_mid<<<dim3(144, 1, 18), 256, 0, stream>>>(q_ws, k_ws, Wr, v, u, br,
                                                U_ws, sc_ws);
    k_bd<<<dim3(SS, BB), 256, 0, stream>>>(rpe, U_ws, mask, sc_ws);
    k_pv<<<dim3(6, 24), 256, 0, stream>>>(sc_ws, v_ws, ctx_ws);
    k_gemm_out<<<dim3(12, 24), 256, 0, stream>>>(ctx_ws, Wf, bf, hs, lnin_ws);
    k_ln<<<dim3(768), 256, 0, stream>>>(lnin_ws, lng, lnb, out);
}